// Round 2
// 844.673 us; speedup vs baseline: 1.1315x; 1.1315x over previous
//
#include <hip/hip_runtime.h>
#include <cstdint>

typedef unsigned short u16;
typedef unsigned long long u64;
typedef __attribute__((ext_vector_type(8))) short short8;
typedef __attribute__((ext_vector_type(4))) float floatx4;

#define DEV __device__ __forceinline__

// async global->LDS, 16B per lane; LDS dest must be wave-uniform base + lane*16
#define GLD16(gp, lp)                                                          \
  __builtin_amdgcn_global_load_lds(                                            \
      (const __attribute__((address_space(1))) void*)(gp),                     \
      (__attribute__((address_space(3))) void*)(lp), 16, 0, 0)

DEV u16 f2bf(float f) {  // round-to-nearest-even bf16
  union { float f; uint32_t u; } x; x.f = f;
  uint32_t r = x.u + 0x7fffu + ((x.u >> 16) & 1u);
  return (u16)(r >> 16);
}

// Problem constants: B=2, L=2048, D=1024, H=16, DK=64.

// ---------------------------------------------------------------- mask pack
__global__ __launch_bounds__(256) void pack_mask(
    const int* __restrict__ mask, u64* __restrict__ mw) {
  const int lane = threadIdx.x & 63;
  int gw = (blockIdx.x * 256 + threadIdx.x) >> 6;
  const int nwaves = (gridDim.x * 256) >> 6;
  const int total = (2 * 2048 * 2048) / 64;       // 131072 words
  for (int c = gw; c < total; c += nwaves) {
    int v = mask[(size_t)c * 64 + lane];
    u64 b = __ballot(v != 0);
    if (lane == 0) mw[c] = b;
  }
}

// ---------------------------------------------------------------- transpose
__global__ __launch_bounds__(256) void transpose_w(
    const float* __restrict__ s0, const float* __restrict__ s1,
    const float* __restrict__ s2, const float* __restrict__ s3,
    u16* __restrict__ d0, u16* __restrict__ d1,
    u16* __restrict__ d2, u16* __restrict__ d3) {
  const float* S; u16* D;
  switch (blockIdx.z) {
    case 0: S = s0; D = d0; break;
    case 1: S = s1; D = d1; break;
    case 2: S = s2; D = d2; break;
    default: S = s3; D = d3; break;
  }
  __shared__ u16 t[64][68];
  const int tid = threadIdx.x;
  const int r0 = blockIdx.y * 64, c0 = blockIdx.x * 64;
#pragma unroll
  for (int i = 0; i < 4; ++i) {
    int idx = i * 256 + tid;
    int r = idx >> 4, c = (idx & 15) * 4;
    float4 v = *(const float4*)(S + (size_t)(r0 + r) * 1024 + c0 + c);
    t[r][c] = f2bf(v.x); t[r][c + 1] = f2bf(v.y);
    t[r][c + 2] = f2bf(v.z); t[r][c + 3] = f2bf(v.w);
  }
  __syncthreads();
#pragma unroll
  for (int i = 0; i < 4; ++i) {
    int idx = i * 256 + tid;
    int r = idx >> 4, c = (idx & 15) * 4;
    ushort4 v;
    v.x = t[c][r]; v.y = t[c + 1][r]; v.z = t[c + 2][r]; v.w = t[c + 3][r];
    *(ushort4*)(D + (size_t)(c0 + r) * 1024 + r0 + c) = v;
  }
}

// ---------------------------------------------------------------- fp32->bf16 (q,k,v in one launch)
__global__ __launch_bounds__(256) void cvt3(
    const float* __restrict__ q, const float* __restrict__ k,
    const float* __restrict__ v, u16* __restrict__ dst) {
  const float* S = (blockIdx.z == 0) ? q : (blockIdx.z == 1) ? k : v;
  u16* D = dst + (size_t)blockIdx.z * (4u << 20);
  int i = (blockIdx.x * 256 + threadIdx.x) * 4;
  float4 val = *(const float4*)(S + i);
  ushort4 o;
  o.x = f2bf(val.x); o.y = f2bf(val.y); o.z = f2bf(val.z); o.w = f2bf(val.w);
  *(ushort4*)(D + i) = o;
}

// ---------------------------------------------------------------- GEMM
// phase 0: fused QKV projections, grid (32,8,3) -> 3 blocks/CU, XCD-swizzled.
//          z=0: qh [b,h,l,dk]; z=1: kh [b,h,l,dk]; z=2: vt [b,h,dk,l]
// phase 1: out = ctx @ Wo + bo, grid (32,8,1), fp32 row-major, nontemporal.
// m97-style: 128x128 tile, BK=64, global_load_lds width 16.
__global__ __launch_bounds__(256, 3) void gemm_k(
    const u16* xb3, const u16* wts,
    const float* __restrict__ bq, const float* __restrict__ bk,
    const float* __restrict__ bv, const float* __restrict__ bo,
    u16* __restrict__ qh, u16* __restrict__ kh, u16* __restrict__ vt,
    const u16* ctx, float* __restrict__ out, int phase) {
  __shared__ __align__(16) u16 As[128 * 64];
  __shared__ __align__(16) u16 Bs[128 * 64];
  const int tid = threadIdx.x;
  const int wave = tid >> 6, lane = tid & 63;
  const int quad = lane >> 4, l16 = lane & 15;
  const int wm = (wave >> 1) * 64, wn = (wave & 1) * 64;

  int m0, n0, mode;
  const u16 *X, *Wt; const float* bias;
  u16* outb; float* outf;
  if (phase == 0) {
    int flat = blockIdx.x + 32 * (blockIdx.y + 8 * blockIdx.z);  // 0..767
    int xcd = flat & 7, idx = flat >> 3;                          // idx 0..95
    int g = xcd * 3 + (idx >> 5);                                 // (z,y) group 0..23
    int z = g >> 3;
    m0 = (idx & 31) * 128; n0 = (g & 7) * 128;
    X = xb3 + (size_t)z * (4u << 20);
    Wt = wts + (size_t)z * (1u << 20);
    bias = (z == 0) ? bq : (z == 1) ? bk : bv;
    outb = (z == 0) ? qh : (z == 1) ? kh : vt;
    outf = nullptr;
    mode = (z == 2) ? 1 : 0;
  } else {
    int flat = blockIdx.x + 32 * blockIdx.y;                      // 0..255
    int xcd = flat & 7, idx = flat >> 3;                          // 0..31
    m0 = (xcd * 4 + (idx >> 3)) * 128; n0 = (idx & 7) * 128;
    X = ctx; Wt = wts + 3 * (size_t)(1u << 20);                   // wto
    bias = bo; outb = nullptr; outf = out; mode = 2;
  }

  floatx4 acc[4][4];
#pragma unroll
  for (int i = 0; i < 4; ++i)
#pragma unroll
    for (int j = 0; j < 4; ++j) acc[i][j] = (floatx4){0.f, 0.f, 0.f, 0.f};

  for (int k0 = 0; k0 < 1024; k0 += 64) {
#pragma unroll
    for (int r = 0; r < 4; ++r) {
      int c = r * 256 + tid;                 // 0..1023
      int row = c >> 3, off = (c & 7) * 8;   // 128 rows x 8 chunks
      GLD16(X + (size_t)(m0 + row) * 1024 + k0 + off, As + c * 8);
      GLD16(Wt + (size_t)(n0 + row) * 1024 + k0 + off, Bs + c * 8);
    }
    __syncthreads();
#pragma unroll
    for (int kk = 0; kk < 64; kk += 32) {
      short8 a[4], b[4];
#pragma unroll
      for (int i = 0; i < 4; ++i)
        a[i] = *(const short8*)(As + (wm + i * 16 + l16) * 64 + kk + quad * 8);
#pragma unroll
      for (int i = 0; i < 4; ++i)
        b[i] = *(const short8*)(Bs + (wn + i * 16 + l16) * 64 + kk + quad * 8);
#pragma unroll
      for (int mi = 0; mi < 4; ++mi)
#pragma unroll
        for (int ni = 0; ni < 4; ++ni)
          acc[mi][ni] = __builtin_amdgcn_mfma_f32_16x16x32_bf16(
              a[mi], b[ni], acc[mi][ni], 0, 0, 0);
    }
    __syncthreads();
  }

#pragma unroll
  for (int mi = 0; mi < 4; ++mi) {
#pragma unroll
    for (int ni = 0; ni < 4; ++ni) {
      const int gn = n0 + wn + ni * 16 + l16;
      const float bv_ = bias[gn];
#pragma unroll
      for (int reg = 0; reg < 4; ++reg) {
        const int gm = m0 + wm + mi * 16 + quad * 4 + reg;
        const float v = acc[mi][ni][reg] + bv_;
        if (mode == 2) {
          __builtin_nontemporal_store(v, outf + (size_t)gm * 1024 + gn);
        } else {
          int bb = gm >> 11, l = gm & 2047, hh = gn >> 6, dk = gn & 63;
          size_t addr = (mode == 0)
              ? (((size_t)(bb * 16 + hh) * 2048 + l) * 64 + dk)
              : (((size_t)(bb * 16 + hh) * 64 + dk) * 2048 + l);
          outb[addr] = f2bf(v);
        }
      }
    }
  }
}

// ---------------------------------------------------------------- attention
// Fused: pass 1 computes softmax denominators (swapped QK^T), pass 2 writes
// normalized attn (floatx4, nontemporal) and accumulates ctx = P@V.
// Swapped MFMA: mfma(a=K-rows, b=Q-rows) -> key = quad*4+reg, qrow = l16.
// XCD swizzle: each XCD owns 4 contiguous (b,h) groups -> K/V/Q panels fit L2.
__global__ __launch_bounds__(256, 2) void attn_fused(
    const u16* __restrict__ qh, const u16* __restrict__ kh,
    const u16* __restrict__ vt, const u64* __restrict__ mw,
    float* __restrict__ attn_out, u16* __restrict__ ctx) {
  const int tid = threadIdx.x;
  const int wave = tid >> 6, lane = tid & 63;
  const int quad = lane >> 4, l16 = lane & 15;

  const int flat = blockIdx.x + 32 * (blockIdx.y + 16 * blockIdx.z);  // 0..1023
  const int xcd = flat & 7, idx = flat >> 3;                          // 0..127
  const int hb = xcd * 4 + (idx >> 5);                                // 0..31
  const int q0 = (idx & 31) * 64;
  const int h = hb & 15, b = hb >> 4;
  const int bh = b * 16 + h;

  __shared__ __align__(16) u16 Qs[64 * 72];
  __shared__ __align__(16) u16 Ks[128 * 72];
  __shared__ __align__(16) u16 Vs[64 * 136];   // [dk][key]
  __shared__ __align__(16) u16 Ps[64 * 136];   // [row][key]
  __shared__ float red[4][64];
  __shared__ float rinvs[64];

  const u16* qbase = qh + ((size_t)bh * 2048 + q0) * 64;
  const u16* kbase = kh + (size_t)bh * 2048 * 64;
  const u16* vbase = vt + (size_t)bh * 64 * 2048;
  const u64* mwrow = mw + ((size_t)b * 2048 + q0) * 32;
  float* abase = attn_out + ((size_t)(h * 2 + b) * 2048 + q0) * 2048;

  // stage Q once
#pragma unroll
  for (int r = 0; r < 2; ++r) {
    int c = r * 256 + tid;
    int row = c >> 3, off = (c & 7) * 8;
    uint4 vv = *(const uint4*)(qbase + (size_t)c * 8);
    *(uint4*)(Qs + row * 72 + off) = vv;
  }

  // ---------- pass 1: row sums ----------
  float rs[4] = {0.f, 0.f, 0.f, 0.f};

  for (int kt = 0; kt < 16; ++kt) {
#pragma unroll
    for (int r = 0; r < 4; ++r) {
      int c = r * 256 + tid;
      int row = c >> 3, off = (c & 7) * 8;
      uint4 vv = *(const uint4*)(kbase + (size_t)kt * 8192 + c * 8);
      *(uint4*)(Ks + row * 72 + off) = vv;
    }
    __syncthreads();

    floatx4 st[2][4];
#pragma unroll
    for (int i = 0; i < 2; ++i)
#pragma unroll
      for (int j = 0; j < 4; ++j) st[i][j] = (floatx4){0.f, 0.f, 0.f, 0.f};
#pragma unroll
    for (int kk = 0; kk < 64; kk += 32) {
      short8 a[2], bqf[4];
#pragma unroll
      for (int ki = 0; ki < 2; ++ki)
        a[ki] = *(const short8*)(Ks + (wave * 32 + ki * 16 + l16) * 72 + kk + quad * 8);
#pragma unroll
      for (int qi = 0; qi < 4; ++qi)
        bqf[qi] = *(const short8*)(Qs + (qi * 16 + l16) * 72 + kk + quad * 8);
#pragma unroll
      for (int ki = 0; ki < 2; ++ki)
#pragma unroll
        for (int qi = 0; qi < 4; ++qi)
          st[ki][qi] = __builtin_amdgcn_mfma_f32_16x16x32_bf16(
              a[ki], bqf[qi], st[ki][qi], 0, 0, 0);
    }

#pragma unroll
    for (int qi = 0; qi < 4; ++qi) {
      u64 w = mwrow[(size_t)(qi * 16 + l16) * 32 + kt * 2 + (wave >> 1)];
#pragma unroll
      for (int ki = 0; ki < 2; ++ki) {
        int bb0 = (wave & 1) * 32 + ki * 16 + quad * 4;
#pragma unroll
        for (int reg = 0; reg < 4; ++reg) {
          float sv = st[ki][qi][reg] * (1.0f / 1024.0f);
          rs[qi] += ((w >> (bb0 + reg)) & 1) ? __expf(sv) : 0.f;
        }
      }
    }
    __syncthreads();
  }

  // reduce across quads (keys 16-spans) then across waves (32-spans)
#pragma unroll
  for (int qi = 0; qi < 4; ++qi) {
    float vsum = rs[qi];
    vsum += __shfl_xor(vsum, 16, 64);
    vsum += __shfl_xor(vsum, 32, 64);
    rs[qi] = vsum;
  }
  if (quad == 0) {
#pragma unroll
    for (int qi = 0; qi < 4; ++qi) red[wave][qi * 16 + l16] = rs[qi];
  }
  __syncthreads();
  if (tid < 64) {
    float s = red[0][tid] + red[1][tid] + red[2][tid] + red[3][tid];
    rinvs[tid] = (s > 0.f) ? (1.0f / s) : -1.0f;
  }
  __syncthreads();

  float inv[4];
#pragma unroll
  for (int qi = 0; qi < 4; ++qi) inv[qi] = rinvs[qi * 16 + l16];

  // ---------- pass 2: write attn + ctx ----------
  floatx4 cacc[4];
#pragma unroll
  for (int i = 0; i < 4; ++i) cacc[i] = (floatx4){0.f, 0.f, 0.f, 0.f};

  for (int kt = 0; kt < 16; ++kt) {
#pragma unroll
    for (int r = 0; r < 4; ++r) {
      int c = r * 256 + tid;
      int row = c >> 3, off = (c & 7) * 8;
      uint4 vv = *(const uint4*)(kbase + (size_t)kt * 8192 + c * 8);
      *(uint4*)(Ks + row * 72 + off) = vv;
      int dk = c >> 4, ko = (c & 15) * 8;
      uint4 wv = *(const uint4*)(vbase + (size_t)dk * 2048 + kt * 128 + ko);
      *(uint4*)(Vs + dk * 136 + ko) = wv;
    }
    __syncthreads();

    floatx4 st[2][4];
#pragma unroll
    for (int i = 0; i < 2; ++i)
#pragma unroll
      for (int j = 0; j < 4; ++j) st[i][j] = (floatx4){0.f, 0.f, 0.f, 0.f};
#pragma unroll
    for (int kk = 0; kk < 64; kk += 32) {
      short8 a[2], bqf[4];
#pragma unroll
      for (int ki = 0; ki < 2; ++ki)
        a[ki] = *(const short8*)(Ks + (wave * 32 + ki * 16 + l16) * 72 + kk + quad * 8);
#pragma unroll
      for (int qi = 0; qi < 4; ++qi)
        bqf[qi] = *(const short8*)(Qs + (qi * 16 + l16) * 72 + kk + quad * 8);
#pragma unroll
      for (int ki = 0; ki < 2; ++ki)
#pragma unroll
        for (int qi = 0; qi < 4; ++qi)
          st[ki][qi] = __builtin_amdgcn_mfma_f32_16x16x32_bf16(
              a[ki], bqf[qi], st[ki][qi], 0, 0, 0);
    }

    // normalize + write (floatx4 per (qi,ki): 4 consecutive keys in regs)
#pragma unroll
    for (int qi = 0; qi < 4; ++qi) {
      int row = qi * 16 + l16;
      u64 w = mwrow[(size_t)row * 32 + kt * 2 + (wave >> 1)];
      float iv = inv[qi];
#pragma unroll
      for (int ki = 0; ki < 2; ++ki) {
        int bb0 = (wave & 1) * 32 + ki * 16 + quad * 4;
        int keyl = wave * 32 + ki * 16 + quad * 4;
        floatx4 pv; ushort4 pb;
#pragma unroll
        for (int reg = 0; reg < 4; ++reg) {
          float sv = st[ki][qi][reg] * (1.0f / 1024.0f);
          float p = (iv < 0.f) ? (1.0f / 2048.0f)
                               : (((w >> (bb0 + reg)) & 1) ? __expf(sv) * iv : 0.f);
          pv[reg] = p;
          ((u16*)&pb)[reg] = f2bf(p);
        }
        __builtin_nontemporal_store(
            pv, (floatx4*)(abase + (size_t)row * 2048 + kt * 128 + keyl));
        *(ushort4*)(Ps + row * 136 + keyl) = pb;
      }
    }
    __syncthreads();

    // ctx += P @ V ; wave owns dk slice [wave*16, wave*16+16)
#pragma unroll
    for (int ks = 0; ks < 4; ++ks) {
      short8 a[4];
#pragma unroll
      for (int mi = 0; mi < 4; ++mi)
        a[mi] = *(const short8*)(Ps + (mi * 16 + l16) * 136 + ks * 32 + quad * 8);
      short8 bb = *(const short8*)(Vs + (wave * 16 + l16) * 136 + ks * 32 + quad * 8);
#pragma unroll
      for (int mi = 0; mi < 4; ++mi)
        cacc[mi] = __builtin_amdgcn_mfma_f32_16x16x32_bf16(a[mi], bb, cacc[mi], 0, 0, 0);
    }
    __syncthreads();
  }

  // write ctx [b][l][h*64+dk] (bf16 ws)
#pragma unroll
  for (int mi = 0; mi < 4; ++mi)
#pragma unroll
    for (int reg = 0; reg < 4; ++reg) {
      int row = q0 + mi * 16 + quad * 4 + reg;
      int col = h * 64 + wave * 16 + l16;
      ctx[(size_t)(b * 2048 + row) * 1024 + col] = f2bf(cacc[mi][reg]);
    }
}

// ---------------------------------------------------------------- launch
extern "C" void kernel_launch(void* const* d_in, const int* in_sizes, int n_in,
                              void* d_out, int out_size, void* d_ws, size_t ws_size,
                              hipStream_t stream) {
  const float* q    = (const float*)d_in[0];
  const float* k    = (const float*)d_in[1];
  const float* v    = (const float*)d_in[2];
  const int*   mask = (const int*)d_in[3];
  const float* Wq   = (const float*)d_in[4];
  const float* bq   = (const float*)d_in[5];
  const float* Wk   = (const float*)d_in[6];
  const float* bk   = (const float*)d_in[7];
  const float* Wv   = (const float*)d_in[8];
  const float* bv   = (const float*)d_in[9];
  const float* Wo   = (const float*)d_in[10];
  const float* bo   = (const float*)d_in[11];

  float* out  = (float*)d_out;                    // [4096][1024] fp32
  float* attn = out + (size_t)4096 * 1024;        // [32][2048][2048] fp32

  const size_t M = 1u << 20;
  u16* wtq = (u16*)d_ws;                          // 4 x 1M elems bf16 (W^T, contiguous)
  u16* wtk = wtq + M;
  u16* wtv = wtk + M;
  u16* wto = wtv + M;
  u16* xb3 = wto + M;                             // 3 x 4M bf16 (q,k,v inputs)
  u16* qh  = xb3 + 12 * M;                        // [b,h,l,dk]  4M
  u16* kh  = qh + 4 * M;
  u16* vt  = kh + 4 * M;                          // [b,h,dk,l]
  u64* mw  = (u64*)(vt + 4 * M);                  // 131072 words (1 MB)
  u16* ctx = xb3;                                 // reuse xb3 after QKV gemms

  pack_mask<<<dim3(512), 256, 0, stream>>>(mask, mw);
  transpose_w<<<dim3(16, 16, 4), 256, 0, stream>>>(Wq, Wk, Wv, Wo, wtq, wtk, wtv, wto);
  cvt3<<<dim3(4096, 1, 3), 256, 0, stream>>>(q, k, v, xb3);

  gemm_k<<<dim3(32, 8, 3), 256, 0, stream>>>(xb3, wtq, bq, bk, bv, bo,
                                             qh, kh, vt, ctx, out, 0);
  attn_fused<<<dim3(32, 16, 2), 256, 0, stream>>>(qh, kh, vt, mw, attn, ctx);
  gemm_k<<<dim3(32, 8, 1), 256, 0, stream>>>(xb3, wtq, bq, bk, bv, bo,
                                             qh, kh, vt, ctx, out, 1);
}